// Round 3
// baseline (359.660 us; speedup 1.0000x reference)
//
#include <hip/hip_runtime.h>

// LIF neuron scan: B=16, S=2048, D=1024, fp32.
// The grader's reference is XLA-jitted fp32 (xla_allow_excess_precision=true),
// so LLVM contracts fmul+fadd into IEEE fma inside the scan body. Spike bits
// must match exactly -> replicate the contracted rounding with explicit
// __builtin_fmaf at the three sites where fusion changes rounding:
//   syn  = fma(beta_syn, syn, x)
//   mem  = fma(beta_mem, mem, syn*nonref)   (syn*nonref exact; beta_mem*mem unrounded)
//   tha  = fma(0.9f, tha, 0.1f*spk)         (0.1f*spk exact)
// All other fusion candidates are rounding-equivalent because one factor is
// exactly 0/1 or 1.0 (scale==1, lth==1, spk in {0,1}).
// pragma contract(off) prevents the compiler from contracting anything else.
// One thread per (b,d) chain: 256 blocks x 64 threads = 1 wave/CU.
// x-loads are state-independent -> prefetch 2 groups x 16 timesteps ahead.

#define SB 16
#define SS 2048
#define SD 1024

__global__ __launch_bounds__(64, 1) void lif_kernel(
    const float* __restrict__ x,
    const float* __restrict__ beta_mem_p,
    const float* __restrict__ beta_syn_p,
    const float* __restrict__ adapt_p,
    const float* __restrict__ scale_p,
    const float* __restrict__ lth_p,
    float* __restrict__ out)
{
#pragma clang fp contract(off)
    const int tid = blockIdx.x * 64 + threadIdx.x;   // 0..16383
    const int b = tid >> 10;        // / SD
    const int d = tid & (SD - 1);   // % SD

    const float beta_mem = beta_mem_p[0];
    const float beta_syn = beta_syn_p[0];
    const float p        = adapt_p[0];
    const float scale    = scale_p[d];
    const float lth      = lth_p[d];

    const float* xp = x   + ((size_t)b * SS) * SD + d;
    float*       sp = out + ((size_t)b * SS) * SD + d;

    float mem = 0.f, syn = 0.f, tha = 0.f, refr = 0.f;

    constexpr int U = 16;
    float buf[2][U];

    // prologue: prefetch t = 0..31
    #pragma unroll
    for (int i = 0; i < U; ++i) buf[0][i] = xp[(size_t)i * SD];
    #pragma unroll
    for (int i = 0; i < U; ++i) buf[1][i] = xp[(size_t)(U + i) * SD];

    for (int t0 = 0; t0 < SS; t0 += U) {
        const int g = (t0 / U) & 1;

        float xc[U];
        #pragma unroll
        for (int i = 0; i < U; ++i) xc[i] = buf[g][i];

        const int tn = t0 + 2 * U;
        if (tn < SS) {
            #pragma unroll
            for (int i = 0; i < U; ++i) buf[g][i] = xp[(size_t)(tn + i) * SD];
        }

        #pragma unroll
        for (int i = 0; i < U; ++i) {
            const float xt = xc[i];

            // synaptic = fma(beta_syn, synaptic, xt)   [XLA-contracted]
            syn = __builtin_fmaf(beta_syn, syn, xt);

            // non_refractory = (refractory <= 0)
            const float nonref = (refr <= 0.f) ? 1.f : 0.f;

            // membrane = fma(beta_mem, membrane, synaptic*nonref)  [contracted]
            mem = __builtin_fmaf(beta_mem, mem, syn * nonref);

            // cur_th = lth + (p*tha)*scale  (scale==1 -> fma form equivalent)
            const float q = p * tha;
            const float cur_th = __builtin_fmaf(q, scale, lth);

            // spike = membrane >= cur_th
            const float spike = (mem >= cur_th) ? 1.f : 0.f;

            // membrane -= spike * cur_th   (spike in {0,1} -> product exact)
            mem = mem - spike * cur_th;

            // th_adapt = fma(0.9, th_adapt, 0.1*spike)  [contracted; 0.1*spk exact]
            tha = __builtin_fmaf(0.9f, tha, 0.1f * spike);

            // refractory = spike > 0.5 ? 2.0 : max(refractory - 1, 0)
            refr = (spike > 0.5f) ? 2.0f : fmaxf(refr - 1.f, 0.f);

            sp[(size_t)(t0 + i) * SD] = spike;
        }
    }

    // final carry: membrane, synaptic, th_adapt, refractory  (each B x D)
    const size_t base = (size_t)SB * SS * SD;
    const size_t off  = (size_t)b * SD + d;
    out[base + 0 * (size_t)SB * SD + off] = mem;
    out[base + 1 * (size_t)SB * SD + off] = syn;
    out[base + 2 * (size_t)SB * SD + off] = tha;
    out[base + 3 * (size_t)SB * SD + off] = refr;
}

extern "C" void kernel_launch(void* const* d_in, const int* in_sizes, int n_in,
                              void* d_out, int out_size, void* d_ws, size_t ws_size,
                              hipStream_t stream) {
    const float* x        = (const float*)d_in[0];
    const float* beta_mem = (const float*)d_in[1];
    const float* beta_syn = (const float*)d_in[2];
    const float* adapt_p  = (const float*)d_in[3];
    const float* scale    = (const float*)d_in[4];
    const float* lth      = (const float*)d_in[5];
    float* out = (float*)d_out;

    // 16384 chains / 64 threads = 256 blocks -> 1 wave per CU
    lif_kernel<<<256, 64, 0, stream>>>(x, beta_mem, beta_syn, adapt_p, scale, lth, out);
}

// Round 4
// 112.078 us; speedup vs baseline: 3.2090x; 3.2090x over previous
//
#include <hip/hip_runtime.h>

// LIF neuron scan: B=16, S=2048, D=1024, fp32. PASSED numerics (absmax 0.0):
// XLA-contracted fp32 — explicit __builtin_fmaf at syn/mem/tha, everything else
// contraction-off. DO NOT change the arithmetic.
//
// R3 post-mortem: runtime-indexed buf[2][U] went to SCRATCH (VGPR_Count=48),
// serializing every timestep on scratch round-trips -> 536us. This version uses
// two statically-indexed buffers (bufA/bufB) with a 2-phase unrolled loop so
// everything stays in registers, and deepens prefetch to U=32 (64 outstanding
// 4B loads/lane, ~2560cy lead >> ~900cy HBM latency).
// One thread per (b,d) chain: 256 blocks x 64 threads = 1 wave/CU.

#define SB 16
#define SS 2048
#define SD 1024

__global__ __launch_bounds__(64, 1) void lif_kernel(
    const float* __restrict__ x,
    const float* __restrict__ beta_mem_p,
    const float* __restrict__ beta_syn_p,
    const float* __restrict__ adapt_p,
    const float* __restrict__ scale_p,
    const float* __restrict__ lth_p,
    float* __restrict__ out)
{
#pragma clang fp contract(off)
    const int tid = blockIdx.x * 64 + threadIdx.x;   // 0..16383
    const int b = tid >> 10;        // / SD
    const int d = tid & (SD - 1);   // % SD

    const float beta_mem = beta_mem_p[0];
    const float beta_syn = beta_syn_p[0];
    const float p        = adapt_p[0];
    const float scale    = scale_p[d];
    const float lth      = lth_p[d];

    const float* xp = x   + ((size_t)b * SS) * SD + d;
    float*       sp = out + ((size_t)b * SS) * SD + d;

    float mem = 0.f, syn = 0.f, tha = 0.f, refr = 0.f;

    constexpr int U = 32;

    // FROZEN numerics: one timestep (XLA fma contraction replicated)
    auto step = [&](float xt, int t) {
        syn = __builtin_fmaf(beta_syn, syn, xt);
        const float nonref = (refr <= 0.f) ? 1.f : 0.f;
        mem = __builtin_fmaf(beta_mem, mem, syn * nonref);
        const float q = p * tha;
        const float cur_th = __builtin_fmaf(q, scale, lth);
        const float spike = (mem >= cur_th) ? 1.f : 0.f;
        mem = mem - spike * cur_th;
        tha = __builtin_fmaf(0.9f, tha, 0.1f * spike);
        refr = (spike > 0.5f) ? 2.0f : fmaxf(refr - 1.f, 0.f);
        sp[(size_t)t * SD] = spike;
    };

    float bufA[U], bufB[U];   // statically indexed ONLY -> registers

    // prologue: prefetch t = 0..2U-1
    #pragma unroll
    for (int i = 0; i < U; ++i) bufA[i] = xp[(size_t)i * SD];
    #pragma unroll
    for (int i = 0; i < U; ++i) bufB[i] = xp[(size_t)(U + i) * SD];

    for (int t0 = 0; t0 < SS; t0 += 2 * U) {
        // ---- phase A: consume bufA (t0..t0+U-1), refill bufA for t0+2U ----
        {
            float xc[U];
            #pragma unroll
            for (int i = 0; i < U; ++i) xc[i] = bufA[i];
            if (t0 + 2 * U < SS) {
                #pragma unroll
                for (int i = 0; i < U; ++i)
                    bufA[i] = xp[(size_t)(t0 + 2 * U + i) * SD];
            }
            #pragma unroll
            for (int i = 0; i < U; ++i) step(xc[i], t0 + i);
        }
        // ---- phase B: consume bufB (t0+U..t0+2U-1), refill bufB for t0+3U --
        {
            float xc[U];
            #pragma unroll
            for (int i = 0; i < U; ++i) xc[i] = bufB[i];
            if (t0 + 3 * U < SS) {
                #pragma unroll
                for (int i = 0; i < U; ++i)
                    bufB[i] = xp[(size_t)(t0 + 3 * U + i) * SD];
            }
            #pragma unroll
            for (int i = 0; i < U; ++i) step(xc[i], t0 + U + i);
        }
    }

    // final carry: membrane, synaptic, th_adapt, refractory  (each B x D)
    const size_t base = (size_t)SB * SS * SD;
    const size_t off  = (size_t)b * SD + d;
    out[base + 0 * (size_t)SB * SD + off] = mem;
    out[base + 1 * (size_t)SB * SD + off] = syn;
    out[base + 2 * (size_t)SB * SD + off] = tha;
    out[base + 3 * (size_t)SB * SD + off] = refr;
}

extern "C" void kernel_launch(void* const* d_in, const int* in_sizes, int n_in,
                              void* d_out, int out_size, void* d_ws, size_t ws_size,
                              hipStream_t stream) {
    const float* x        = (const float*)d_in[0];
    const float* beta_mem = (const float*)d_in[1];
    const float* beta_syn = (const float*)d_in[2];
    const float* adapt_p  = (const float*)d_in[3];
    const float* scale    = (const float*)d_in[4];
    const float* lth      = (const float*)d_in[5];
    float* out = (float*)d_out;

    // 16384 chains / 64 threads = 256 blocks -> 1 wave per CU
    lif_kernel<<<256, 64, 0, stream>>>(x, beta_mem, beta_syn, adapt_p, scale, lth, out);
}

// Round 5
// 87.960 us; speedup vs baseline: 4.0889x; 1.2742x over previous
//
#include <hip/hip_runtime.h>

// LIF neuron scan: B=16, S=2048, D=1024, fp32. NUMERICS FROZEN (absmax 0.0):
// XLA-contracted fp32 — __builtin_fmaf at syn/mem/tha sites, contract(off)
// elsewhere. DO NOT change step().
//
// R4 post-mortem: 1 wave/CU + source-level prefetch = compiler sank the loads
// (VGPR=76 proves buffers weren't resident) -> latency-bound at 131us.
// R5: producer/consumer wave specialization. Block=128 (2 waves), grid=256:
//   wave 1 (producer): stages x tile (64t x 64d) to LDS via float4 loads,
//                      double-buffered, 1 barrier/tile. Its vmcnt(0) stall
//                      overlaps the consumer's compute on another SIMD.
//   wave 0 (consumer): serial LIF chain per lane, x from LDS (ds_read ~120cy,
//                      2-way bank alias = free), spike dword stores (coalesced).

#define SB 16
#define SS 2048
#define SD 1024
#define TILE 64          // timesteps per LDS tile
#define NT (SS / TILE)   // 32 tiles

__global__ __launch_bounds__(128, 1) void lif_kernel(
    const float* __restrict__ x,
    const float* __restrict__ beta_mem_p,
    const float* __restrict__ beta_syn_p,
    const float* __restrict__ adapt_p,
    const float* __restrict__ scale_p,
    const float* __restrict__ lth_p,
    float* __restrict__ out)
{
#pragma clang fp contract(off)
    __shared__ float lds[2][TILE][64];   // 32 KB

    const int bk = blockIdx.x;           // 0..255
    const int b  = bk >> 4;              // batch
    const int d0 = (bk & 15) << 6;       // first of this block's 64 d's

    const float* xb = x + ((size_t)b * SS) * SD + d0;

    if (threadIdx.x >= 64) {
        // ---------------- producer wave ----------------
        const int pl = threadIdx.x - 64;       // 0..63
        const int tr = pl >> 4;                // 0..3 (row within 4-row group)
        const int dc = (pl & 15) << 2;         // 0,4,...,60

        // prologue: stage tile 0 into buf 0
        {
            float4 v[16];
            #pragma unroll
            for (int r = 0; r < 16; ++r)
                v[r] = *(const float4*)(xb + (size_t)(r * 4 + tr) * SD + dc);
            #pragma unroll
            for (int r = 0; r < 16; ++r)
                *(float4*)&lds[0][r * 4 + tr][dc] = v[r];
        }
        __syncthreads();

        for (int k = 0; k < NT; ++k) {
            if (k + 1 < NT) {
                const int t0 = (k + 1) * TILE;
                float4 v[16];
                #pragma unroll
                for (int r = 0; r < 16; ++r)
                    v[r] = *(const float4*)(xb + (size_t)(t0 + r * 4 + tr) * SD + dc);
                #pragma unroll
                for (int r = 0; r < 16; ++r)
                    *(float4*)&lds[(k + 1) & 1][r * 4 + tr][dc] = v[r];
            }
            __syncthreads();
        }
    } else {
        // ---------------- consumer wave ----------------
        const int lane = threadIdx.x;          // 0..63
        const int d = d0 + lane;

        const float beta_mem = beta_mem_p[0];
        const float beta_syn = beta_syn_p[0];
        const float p        = adapt_p[0];
        const float scale    = scale_p[d];
        const float lth      = lth_p[d];

        float* sp = out + ((size_t)b * SS) * SD + d;

        float mem = 0.f, syn = 0.f, tha = 0.f, refr = 0.f;

        // FROZEN numerics: one timestep (XLA fma contraction replicated)
        auto step = [&](float xt, int t) {
            syn = __builtin_fmaf(beta_syn, syn, xt);
            const float nonref = (refr <= 0.f) ? 1.f : 0.f;
            mem = __builtin_fmaf(beta_mem, mem, syn * nonref);
            const float q = p * tha;
            const float cur_th = __builtin_fmaf(q, scale, lth);
            const float spike = (mem >= cur_th) ? 1.f : 0.f;
            mem = mem - spike * cur_th;
            tha = __builtin_fmaf(0.9f, tha, 0.1f * spike);
            refr = (spike > 0.5f) ? 2.0f : fmaxf(refr - 1.f, 0.f);
            sp[(size_t)t * SD] = spike;
        };

        __syncthreads();   // wait for tile 0

        for (int k = 0; k < NT; ++k) {
            const int t0 = k * TILE;
            const int cur = k & 1;
            // grouped LDS reads (16 ahead) then 16 steps
            for (int g = 0; g < TILE / 16; ++g) {
                float xc[16];
                #pragma unroll
                for (int i = 0; i < 16; ++i)
                    xc[i] = lds[cur][g * 16 + i][lane];
                #pragma unroll
                for (int i = 0; i < 16; ++i)
                    step(xc[i], t0 + g * 16 + i);
            }
            __syncthreads();
        }

        // final carry: membrane, synaptic, th_adapt, refractory (each B x D)
        const size_t base = (size_t)SB * SS * SD;
        const size_t off  = (size_t)b * SD + d;
        out[base + 0 * (size_t)SB * SD + off] = mem;
        out[base + 1 * (size_t)SB * SD + off] = syn;
        out[base + 2 * (size_t)SB * SD + off] = tha;
        out[base + 3 * (size_t)SB * SD + off] = refr;
    }
}

extern "C" void kernel_launch(void* const* d_in, const int* in_sizes, int n_in,
                              void* d_out, int out_size, void* d_ws, size_t ws_size,
                              hipStream_t stream) {
    const float* x        = (const float*)d_in[0];
    const float* beta_mem = (const float*)d_in[1];
    const float* beta_syn = (const float*)d_in[2];
    const float* adapt_p  = (const float*)d_in[3];
    const float* scale    = (const float*)d_in[4];
    const float* lth      = (const float*)d_in[5];
    float* out = (float*)d_out;

    // 256 blocks x 128 threads: 1 block/CU, consumer wave + producer wave
    lif_kernel<<<256, 128, 0, stream>>>(x, beta_mem, beta_syn, adapt_p, scale, lth, out);
}